// Round 1
// baseline (147.331 us; speedup 1.0000x reference)
//
#include <hip/hip_runtime.h>

// x: [16, 64, 256, 256] f32 in [0,255)
// out = x * ((floor(x/8) != dominant_bin[bc]) * mean[bc])
// dominant_bin from histc binning: clip(floor(x * 32/255), 0, 31), argmax first-tie.

#define NBINS 32
#define HW 65536          // 256*256
#define NCHAN 1024        // 16*64
#define NREP 8            // histogram replicas (per half-wave)

__global__ __launch_bounds__(256) void chan_stats_kernel(
    const float* __restrict__ x, int* __restrict__ dom, float* __restrict__ mean)
{
    __shared__ unsigned int hist[NREP][NBINS];
    __shared__ float ssum[4];

    const int bc   = blockIdx.x;
    const int tid  = threadIdx.x;
    const int wave = tid >> 6;
    const int lane = tid & 63;
    const int rep  = tid >> 5;   // half-wave replica id, 0..7

    // zero the 8*32 = 256 counters (exactly one per thread)
    ((unsigned int*)hist)[tid] = 0u;
    __syncthreads();

    const float4* __restrict__ xp =
        (const float4*)(x + (size_t)bc * (size_t)HW);
    const float scale = 32.0f / 255.0f;   // same f32 constant as the reference

    float sum = 0.0f;
    // 65536 / 4 = 16384 float4 per channel; 256 threads -> 64 iterations
    #pragma unroll 4
    for (int it = 0; it < 64; ++it) {
        float4 v = xp[it * 256 + tid];
        sum += v.x + v.y + v.z + v.w;
        int b0 = (int)floorf(v.x * scale);
        int b1 = (int)floorf(v.y * scale);
        int b2 = (int)floorf(v.z * scale);
        int b3 = (int)floorf(v.w * scale);
        b0 = min(max(b0, 0), NBINS - 1);
        b1 = min(max(b1, 0), NBINS - 1);
        b2 = min(max(b2, 0), NBINS - 1);
        b3 = min(max(b3, 0), NBINS - 1);
        atomicAdd(&hist[rep][b0], 1u);
        atomicAdd(&hist[rep][b1], 1u);
        atomicAdd(&hist[rep][b2], 1u);
        atomicAdd(&hist[rep][b3], 1u);
    }

    // wave reduce the sum (wave = 64 lanes)
    for (int off = 32; off > 0; off >>= 1)
        sum += __shfl_down(sum, off);
    if (lane == 0) ssum[wave] = sum;
    __syncthreads();

    // fold the 8 histogram replicas into hist[0][*]
    if (tid < NBINS) {
        unsigned int c = 0u;
        #pragma unroll
        for (int r = 0; r < NREP; ++r) c += hist[r][tid];
        hist[0][tid] = c;
    }
    __syncthreads();

    if (tid == 0) {
        // argmax with FIRST-occurrence tie-break (jnp.argmax semantics)
        int best = 0;
        unsigned int bestc = hist[0][0];
        #pragma unroll
        for (int i = 1; i < NBINS; ++i) {
            unsigned int c = hist[0][i];
            if (c > bestc) { bestc = c; best = i; }
        }
        dom[bc] = best;
        float s = ssum[0] + ssum[1] + ssum[2] + ssum[3];
        mean[bc] = s * (1.0f / (float)HW);
    }
}

__global__ __launch_bounds__(256) void apply_kernel(
    const float* __restrict__ x, const int* __restrict__ dom,
    const float* __restrict__ mean, float* __restrict__ out)
{
    // 64 blocks per channel: each block covers 256 thr * 4 = 1024 elements
    const int bc = blockIdx.x >> 6;          // uniform per block -> scalar loads
    const int dm = dom[bc];
    const float mn = mean[bc];

    const size_t base = (size_t)blockIdx.x * 1024 + (size_t)threadIdx.x * 4;
    float4 v = *(const float4*)(x + base);
    float4 o;
    // x >= 0 so (int) truncation == floor; x/8 == x*0.125 exactly (pow2)
    o.x = ((int)(v.x * 0.125f) == dm) ? 0.0f : v.x * mn;
    o.y = ((int)(v.y * 0.125f) == dm) ? 0.0f : v.y * mn;
    o.z = ((int)(v.z * 0.125f) == dm) ? 0.0f : v.z * mn;
    o.w = ((int)(v.w * 0.125f) == dm) ? 0.0f : v.w * mn;
    *(float4*)(out + base) = o;
}

extern "C" void kernel_launch(void* const* d_in, const int* in_sizes, int n_in,
                              void* d_out, int out_size, void* d_ws, size_t ws_size,
                              hipStream_t stream) {
    const float* x = (const float*)d_in[0];
    float* out = (float*)d_out;

    int*   dom  = (int*)d_ws;                 // NCHAN ints
    float* mean = (float*)d_ws + NCHAN;       // NCHAN floats

    chan_stats_kernel<<<NCHAN, 256, 0, stream>>>(x, dom, mean);

    const int nblocks = (int)((size_t)NCHAN * HW / 1024);   // 65536
    apply_kernel<<<nblocks, 256, 0, stream>>>(x, dom, mean, out);
}

// Round 2
// 116.933 us; speedup vs baseline: 1.2600x; 1.2600x over previous
//
#include <hip/hip_runtime.h>

// x: [16, 64, 256, 256] f32 in [0,255)
// out = x * ((floor(x/8) != dominant_bin[bc]) * mean[bc])
// dominant_bin from histc binning: clip(floor(x * 32/255), 0, 31), argmax first-tie.
//
// R1 change: nontemporal stores in apply_kernel so the 256 MiB output stream
// does not evict x (exactly L3-sized) from Infinity Cache; x then stays
// L3-resident across replays for both kernels' reads.

#define NBINS 32
#define HW 65536          // 256*256
#define NCHAN 1024        // 16*64
#define NREP 8            // histogram replicas (per half-wave)

typedef float __attribute__((ext_vector_type(4))) fvec4;

__global__ __launch_bounds__(256) void chan_stats_kernel(
    const float* __restrict__ x, int* __restrict__ dom, float* __restrict__ mean)
{
    __shared__ unsigned int hist[NREP][NBINS];
    __shared__ float ssum[4];

    const int bc   = blockIdx.x;
    const int tid  = threadIdx.x;
    const int wave = tid >> 6;
    const int lane = tid & 63;
    const int rep  = tid >> 5;   // half-wave replica id, 0..7

    // zero the 8*32 = 256 counters (exactly one per thread)
    ((unsigned int*)hist)[tid] = 0u;
    __syncthreads();

    const fvec4* __restrict__ xp =
        (const fvec4*)(x + (size_t)bc * (size_t)HW);
    const float scale = 32.0f / 255.0f;   // same f32 constant as the reference

    float sum = 0.0f;
    // 65536 / 4 = 16384 float4 per channel; 256 threads -> 64 iterations
    #pragma unroll 4
    for (int it = 0; it < 64; ++it) {
        fvec4 v = xp[it * 256 + tid];
        sum += v.x + v.y + v.z + v.w;
        int b0 = (int)floorf(v.x * scale);
        int b1 = (int)floorf(v.y * scale);
        int b2 = (int)floorf(v.z * scale);
        int b3 = (int)floorf(v.w * scale);
        b0 = min(max(b0, 0), NBINS - 1);
        b1 = min(max(b1, 0), NBINS - 1);
        b2 = min(max(b2, 0), NBINS - 1);
        b3 = min(max(b3, 0), NBINS - 1);
        atomicAdd(&hist[rep][b0], 1u);
        atomicAdd(&hist[rep][b1], 1u);
        atomicAdd(&hist[rep][b2], 1u);
        atomicAdd(&hist[rep][b3], 1u);
    }

    // wave reduce the sum (wave = 64 lanes)
    for (int off = 32; off > 0; off >>= 1)
        sum += __shfl_down(sum, off);
    if (lane == 0) ssum[wave] = sum;
    __syncthreads();

    // fold the 8 histogram replicas into hist[0][*]
    if (tid < NBINS) {
        unsigned int c = 0u;
        #pragma unroll
        for (int r = 0; r < NREP; ++r) c += hist[r][tid];
        hist[0][tid] = c;
    }
    __syncthreads();

    if (tid == 0) {
        // argmax with FIRST-occurrence tie-break (jnp.argmax semantics)
        int best = 0;
        unsigned int bestc = hist[0][0];
        #pragma unroll
        for (int i = 1; i < NBINS; ++i) {
            unsigned int c = hist[0][i];
            if (c > bestc) { bestc = c; best = i; }
        }
        dom[bc] = best;
        float s = ssum[0] + ssum[1] + ssum[2] + ssum[3];
        mean[bc] = s * (1.0f / (float)HW);
    }
}

__global__ __launch_bounds__(256) void apply_kernel(
    const float* __restrict__ x, const int* __restrict__ dom,
    const float* __restrict__ mean, float* __restrict__ out)
{
    // 64 blocks per channel: each block covers 256 thr * 4 = 1024 elements
    const int bc = blockIdx.x >> 6;          // uniform per block -> scalar loads
    const int dm = dom[bc];
    const float mn = mean[bc];

    const size_t base = (size_t)blockIdx.x * 1024 + (size_t)threadIdx.x * 4;
    fvec4 v = *(const fvec4*)(x + base);
    fvec4 o;
    // x >= 0 so (int) truncation == floor; x/8 == x*0.125 exactly (pow2)
    o.x = ((int)(v.x * 0.125f) == dm) ? 0.0f : v.x * mn;
    o.y = ((int)(v.y * 0.125f) == dm) ? 0.0f : v.y * mn;
    o.z = ((int)(v.z * 0.125f) == dm) ? 0.0f : v.z * mn;
    o.w = ((int)(v.w * 0.125f) == dm) ? 0.0f : v.w * mn;
    // nontemporal: stream the output past L3 so x stays Infinity-Cache-resident
    __builtin_nontemporal_store(o, (fvec4*)(out + base));
}

extern "C" void kernel_launch(void* const* d_in, const int* in_sizes, int n_in,
                              void* d_out, int out_size, void* d_ws, size_t ws_size,
                              hipStream_t stream) {
    const float* x = (const float*)d_in[0];
    float* out = (float*)d_out;

    int*   dom  = (int*)d_ws;                 // NCHAN ints
    float* mean = (float*)d_ws + NCHAN;       // NCHAN floats

    chan_stats_kernel<<<NCHAN, 256, 0, stream>>>(x, dom, mean);

    const int nblocks = (int)((size_t)NCHAN * HW / 1024);   // 65536
    apply_kernel<<<nblocks, 256, 0, stream>>>(x, dom, mean, out);
}